// Round 6
// baseline (438.209 us; speedup 1.0000x reference)
//
#include <hip/hip_runtime.h>
#include <math.h>

// ---------------------------------------------------------------------------
// GraphSAGE fraud detector. CSR-gather aggregation + bf16 MFMA GEMMs.
// R22: XCD-sliced gather_mean_512. R21 profile: gemm2_breg left the top-5;
// gather_mean_512 leads at 64.5us with FETCH 188MB vs a 51MB table --
// logical 410MB@7.1TB/s blended, i.e. at the L3+HBM service ceiling. Fix:
// split the 512-col gather into 8 x 64-col slices, slice = blockIdx&7
// (round-robin XCD dispatch) -> each XCD's slice working set is 6.4MB vs
// its 4MB private L2 (~60% L2 hits); rest falls to L3 (fully resident).
// Per edge: half-wave reads 128B (lane=32*parity+col), 2 edges/instr,
// 8 pairs unrolled (8 outstanding loads/lane, unchanged ILP depth);
// halves merge via shfl_xor(32); lanes 0-31 write the 128B output slice.
// If %8->XCD doesn't hold this degrades to today's L3-resident behavior
// (neutral); FETCH_SIZE adjudicates.
// R21 (kept): layer-2 GEMM A-in-LDS(3x8KB)+B-in-regs from fragment-packed
// Wf (off = ((((t*8+g)*4+nt)*4+quad)*16+cl)*8+j); vmcnt(5) gate.
// MFMA 16x16x32 bf16: A-frag A[m=lane&15][k=quad*8+j]; C/D col=lane&15,
// row=quad*4+reg (m89/m97-verified layouts).
// ---------------------------------------------------------------------------

typedef __attribute__((ext_vector_type(8))) short bf16x8;   // 8 bf16, 4 VGPRs
typedef __attribute__((ext_vector_type(4))) float f32x4;

static inline int ceil_div(int a, int b) { return (a + b - 1) / b; }

__device__ inline float bf2f_lo(unsigned u) { return __builtin_bit_cast(float, u << 16); }
__device__ inline float bf2f_hi(unsigned u) { return __builtin_bit_cast(float, u & 0xffff0000u); }
__device__ inline unsigned f2bf(float f) {   // RNE round to bf16, bits in low 16
    unsigned u = __builtin_bit_cast(unsigned, f);
    u += 0x7fffu + ((u >> 16) & 1u);
    return u >> 16;
}

// async global->LDS, 16 B per lane; LDS dest = wave-uniform base + lane*16
#define GLOAD_LDS16(gp, lp)                                                   \
    __builtin_amdgcn_global_load_lds(                                         \
        (__attribute__((address_space(1))) void*)(gp),                        \
        (__attribute__((address_space(3))) void*)(lp), 16, 0, 0)

// ---------------- fused cvt(x,W1,W2) + deg histogram ----------------
// W2 branch packs into the Wf fragment-linear layout (see header).

__global__ void cvt3_hist_kernel(const float* __restrict__ a, unsigned short* __restrict__ ao, int na4,
                                 const float* __restrict__ b, unsigned short* __restrict__ bo, int nb4,
                                 const float* __restrict__ c, unsigned short* __restrict__ co, int nc4,
                                 const int* __restrict__ dst, int* __restrict__ deg, int E,
                                 int cvt_blocks) {
    if ((int)blockIdx.x < cvt_blocks) {
        int i = blockIdx.x * 256 + threadIdx.x;
        if (i < na4 + nb4) {
            const float* in; unsigned short* out; int k;
            if (i < na4) { in = a; out = ao; k = i; }
            else         { in = b; out = bo; k = i - na4; }
            float4 v = ((const float4*)in)[k];
            ushort4 o;
            o.x = (unsigned short)f2bf(v.x);
            o.y = (unsigned short)f2bf(v.y);
            o.z = (unsigned short)f2bf(v.z);
            o.w = (unsigned short)f2bf(v.w);
            ((ushort4*)out)[k] = o;
        } else if (i < na4 + nb4 + nc4) {
            int kk = i - na4 - nb4;            // float4 idx into W2 [512][1024]
            float4 v = ((const float4*)c)[kk];
            ushort4 o;
            o.x = (unsigned short)f2bf(v.x);
            o.y = (unsigned short)f2bf(v.y);
            o.z = (unsigned short)f2bf(v.z);
            o.w = (unsigned short)f2bf(v.w);
            const int cc = kk >> 8;            // row (col of GEMM-B), 0..511
            const int kq = kk & 255;           // float4 within row
            const int t    = kq >> 3;          // k-tile of 32
            const int quad = (kq >> 1) & 3;
            const int j0   = (kq & 1) * 4;
            const int g  = cc >> 6, nt = (cc >> 4) & 3, cl = cc & 15;
            const size_t off =
                ((((size_t)(t * 8 + g) * 4 + nt) * 4 + quad) * 16 + cl) * 8 + j0;
            *(ushort4*)(co + off) = o;
        }
    } else {
        int e = (blockIdx.x - cvt_blocks) * 256 + threadIdx.x;
        if (e < E) atomicAdd(&deg[dst[e]], 1);
    }
}

// ---------------- CSR build ----------------

// per-1024-chunk sums
__global__ __launch_bounds__(256) void chunk_reduce(const int* __restrict__ deg,
                                                    int* __restrict__ partial, int N) {
    int base = blockIdx.x * 1024;
    int s = 0;
    for (int i = threadIdx.x; i < 1024; i += 256) {
        int idx = base + i;
        if (idx < N) s += deg[idx];
    }
    #pragma unroll
    for (int off = 32; off; off >>= 1) s += __shfl_down(s, off);
    __shared__ int ws[4];
    if ((threadIdx.x & 63) == 0) ws[threadIdx.x >> 6] = s;
    __syncthreads();
    if (threadIdx.x == 0) partial[blockIdx.x] = ws[0] + ws[1] + ws[2] + ws[3];
}

// exclusive scan of P<=64 partials (one wave); writes rowstart[N]=total
__global__ void partial_scan(int* __restrict__ partial, int* __restrict__ rowstartN, int P) {
    int lane = threadIdx.x;
    int v = (lane < P) ? partial[lane] : 0;
    int incl = v;
    #pragma unroll
    for (int off = 1; off < 64; off <<= 1) {
        int t = __shfl_up(incl, off);
        if (lane >= off) incl += t;
    }
    if (lane < P) partial[lane] = incl - v;
    if (lane == 63) *rowstartN = incl;
}

// per-chunk exclusive scan + global offset; writes rowstart and cursor
__global__ __launch_bounds__(256) void chunk_scan(const int* __restrict__ deg,
                                                  const int* __restrict__ partial,
                                                  int* __restrict__ rowstart,
                                                  int* __restrict__ cursor, int N) {
    int base = blockIdx.x * 1024 + threadIdx.x * 4;
    int v[4];
    #pragma unroll
    for (int j = 0; j < 4; ++j) {
        int i = base + j;
        v[j] = (i < N) ? deg[i] : 0;
    }
    int mysum = v[0] + v[1] + v[2] + v[3];
    int incl = mysum;
    int lane = threadIdx.x & 63, wave = threadIdx.x >> 6;
    #pragma unroll
    for (int off = 1; off < 64; off <<= 1) {
        int t = __shfl_up(incl, off);
        if (lane >= off) incl += t;
    }
    __shared__ int ws[4];
    if (lane == 63) ws[wave] = incl;
    __syncthreads();
    int run = partial[blockIdx.x] + incl - mysum;
    for (int w = 0; w < wave; ++w) run += ws[w];
    #pragma unroll
    for (int j = 0; j < 4; ++j) {
        int i = base + j;
        if (i < N) { rowstart[i] = run; cursor[i] = run; }
        run += v[j];
    }
}

__global__ void bucket_kernel(const int* __restrict__ src, const int* __restrict__ dst,
                              int* __restrict__ cursor, int* __restrict__ ebuf, int E) {
    int e = blockIdx.x * 256 + threadIdx.x;
    if (e < E) {
        int pos = atomicAdd(&cursor[dst[e]], 1);
        ebuf[pos] = src[e];
    }
}

// ---------------- gather means ----------------

// one wave per dst row; bf16 xb [N,128] -> bf16 mean [N,128]; fp32 accum
__global__ void gather_mean_128(const int* __restrict__ rowstart, const int* __restrict__ ebuf,
                                const unsigned* __restrict__ featb, unsigned* __restrict__ outb, int N) {
    int w = (blockIdx.x * blockDim.x + threadIdx.x) >> 6;
    int lane = threadIdx.x & 63;
    if (w >= N) return;
    int e0 = rowstart[w], e1 = rowstart[w + 1];
    float ax = 0.0f, ay = 0.0f;
    int i = e0;
    for (; i + 8 <= e1; i += 8) {           // 8-edge unroll for MLP
        unsigned v0 = featb[(size_t)ebuf[i]     * 64 + lane];
        unsigned v1 = featb[(size_t)ebuf[i + 1] * 64 + lane];
        unsigned v2 = featb[(size_t)ebuf[i + 2] * 64 + lane];
        unsigned v3 = featb[(size_t)ebuf[i + 3] * 64 + lane];
        unsigned v4 = featb[(size_t)ebuf[i + 4] * 64 + lane];
        unsigned v5 = featb[(size_t)ebuf[i + 5] * 64 + lane];
        unsigned v6 = featb[(size_t)ebuf[i + 6] * 64 + lane];
        unsigned v7 = featb[(size_t)ebuf[i + 7] * 64 + lane];
        ax += bf2f_lo(v0) + bf2f_lo(v1) + bf2f_lo(v2) + bf2f_lo(v3)
            + bf2f_lo(v4) + bf2f_lo(v5) + bf2f_lo(v6) + bf2f_lo(v7);
        ay += bf2f_hi(v0) + bf2f_hi(v1) + bf2f_hi(v2) + bf2f_hi(v3)
            + bf2f_hi(v4) + bf2f_hi(v5) + bf2f_hi(v6) + bf2f_hi(v7);
    }
    for (; i < e1; ++i) {
        unsigned v = featb[(size_t)ebuf[i] * 64 + lane];
        ax += bf2f_lo(v); ay += bf2f_hi(v);
    }
    float inv = 1.0f / fmaxf((float)(e1 - e0), 1.0f);
    outb[(size_t)w * 64 + lane] = f2bf(ax * inv) | (f2bf(ay * inv) << 16);
}

// XCD-sliced gather: 8 slices x 64 cols; slice = blockIdx&7 (round-robin
// XCD). Per edge a half-wave reads 128B; 2 edges/instr; 8 pairs unrolled.
// Each wave processes ROWS_PW consecutive rows (contiguous ebuf range).
#define ROWS_PW 8
__global__ __launch_bounds__(256) void gather_mean_512s(
    const int* __restrict__ rowstart, const int* __restrict__ ebuf,
    const unsigned* __restrict__ featu,    // h1b as uint [N][256]
    unsigned* __restrict__ outu,           // n2b as uint [N][256]
    int N)
{
    const int s    = blockIdx.x & 7;           // column slice (-> XCD)
    const int wg   = blockIdx.x >> 3;          // row-group index
    const int wv   = threadIdx.x >> 6;
    const int lane = threadIdx.x & 63;
    const int half = lane >> 5;                // 0: even edge, 1: odd edge
    const unsigned cbase = s * 32 + (lane & 31);
    const int row0 = (wg * 4 + wv) * ROWS_PW;
    if (row0 >= N) return;
    const int rend = (row0 + ROWS_PW < N) ? row0 + ROWS_PW : N;
    for (int row = row0; row < rend; ++row) {
        const int e0 = rowstart[row], e1 = rowstart[row + 1];
        float ax = 0.f, ay = 0.f;
        int i = e0;
        for (; i + 16 <= e1; i += 16) {        // 8 pairs in flight
            #pragma unroll
            for (int u = 0; u < 8; ++u) {
                const int e = ebuf[i + u * 2 + half];
                const unsigned v = featu[(size_t)e * 256 + cbase];
                ax += bf2f_lo(v); ay += bf2f_hi(v);
            }
        }
        for (; i < e1; i += 2) {               // pair tail (guarded)
            const int idx = i + half;
            if (idx < e1) {
                const int e = ebuf[idx];
                const unsigned v = featu[(size_t)e * 256 + cbase];
                ax += bf2f_lo(v); ay += bf2f_hi(v);
            }
        }
        ax += __shfl_xor(ax, 32);
        ay += __shfl_xor(ay, 32);
        const float inv = 1.0f / fmaxf((float)(e1 - e0), 1.0f);
        if (half == 0)
            outu[(size_t)row * 256 + cbase] = f2bf(ax * inv) | (f2bf(ay * inv) << 16);
    }
}

// ---------------- bf16 MFMA GEMM (R12-exact: BK=32, XCD swizzle) -----------
// Retained for layer 1 (K=256).
__global__ __launch_bounds__(256) void gemm_mfma(
    const unsigned short* __restrict__ A0,   // [N, K0] bf16
    const unsigned short* __restrict__ A1,   // [N, K1] bf16, K1 == K0
    const unsigned short* __restrict__ W,    // [C, K0+K1] bf16 row-major
    const float* __restrict__ b,             // [C] fp32
    unsigned short* __restrict__ outb,       // [N, C] bf16 (mode 0)
    const float* __restrict__ Wo,            // [C] fp32    (mode 1)
    float* __restrict__ logit,               // [N] fp32    (mode 1)
    int N, int K0, int K1, int C, int mode)
{
    // --- XCD-aware decode ---
    const int nrow = (N + 127) >> 7;
    const int id   = blockIdx.x;
    const int rowb = ((id >> 5) << 3) + (id & 7);   // rslot*8 + xcd
    const int colb = (id >> 3) & 3;
    if (rowb >= nrow) return;

    const int K = K0 + K1;
    const int S = K0;               // row stride of both A0 and A1
    __shared__ short As[2][4096];   // [128][32] per buffer, 8 KB
    __shared__ short Bs[2][4096];

    const int tid  = threadIdx.x;
    const int lane = tid & 63;
    const int wave = tid >> 6;
    const int wm = wave & 1, wn = wave >> 1;
    const int cl = lane & 15, quad = lane >> 4;
    const int row0 = rowb * 128;
    const int col0 = colb * 128;

    // staging: lane = 4r+j; wave w, load i covers tile rows w*32+i*16 .. +16
    const int r = lane >> 2;        // 0..15
    const int j = lane & 3;         // 16B chunk within the row's 64B K-slice
    const int trow0 = wave * 32 + r;
    const int trow1 = trow0 + 16;
    // clamp OOB tile rows to N-1 (loaded garbage discarded by epilogue guard)
    const int ar0 = (row0 + trow0 < N) ? row0 + trow0 : N - 1;
    const int ar1 = (row0 + trow1 < N) ? row0 + trow1 : N - 1;
    const size_t aoff0 = (size_t)ar0 * S + j * 8;
    const size_t aoff1 = (size_t)ar1 * S + j * 8;
    const size_t boff0 = (size_t)(col0 + trow0) * K + j * 8;
    const size_t boff1 = (size_t)(col0 + trow1) * K + j * 8;
    const int lds0 = (wave * 32) * 32;        // shorts; wave-uniform
    const int lds1 = (wave * 32 + 16) * 32;

    f32x4 acc[4][4];
    #pragma unroll
    for (int mt = 0; mt < 4; ++mt)
        #pragma unroll
        for (int nt = 0; nt < 4; ++nt)
            acc[mt][nt] = (f32x4){0.f, 0.f, 0.f, 0.f};

    // prologue: DMA tile 0 into buffer 0
    GLOAD_LDS16(A0 + aoff0, &As[0][lds0]);
    GLOAD_LDS16(A0 + aoff1, &As[0][lds1]);
    GLOAD_LDS16(W  + boff0, &Bs[0][lds0]);
    GLOAD_LDS16(W  + boff1, &Bs[0][lds1]);

    const int iters = K >> 5;
    for (int i = 0; i < iters; ++i) {
        const int cur = i & 1;
        // barrier drains tile i's DMA (vmcnt0) and fences tile i-1 frag reads
        __syncthreads();
        if (i + 1 < iters) {
            const int kn = (i + 1) << 5;
            const unsigned short* Ab = (kn < K0) ? (A0 + kn) : (A1 + (kn - K0));
            const unsigned short* Wb = W + kn;
            const int nb = cur ^ 1;
            GLOAD_LDS16(Ab + aoff0, &As[nb][lds0]);
            GLOAD_LDS16(Ab + aoff1, &As[nb][lds1]);
            GLOAD_LDS16(Wb + boff0, &Bs[nb][lds0]);
            GLOAD_LDS16(Wb + boff1, &Bs[nb][lds1]);
        }

        bf16x8 af[4], bfr[4];
        #pragma unroll
        for (int mt = 0; mt < 4; ++mt)
            af[mt] = *(const bf16x8*)&As[cur][(wm * 64 + mt * 16 + cl) * 32 + quad * 8];
        #pragma unroll
        for (int nt = 0; nt < 4; ++nt)
            bfr[nt] = *(const bf16x8*)&Bs[cur][(wn * 64 + nt * 16 + cl) * 32 + quad * 8];

        #pragma unroll
        for (int mt = 0; mt < 4; ++mt)
            #pragma unroll
            for (int nt = 0; nt < 4; ++nt)
                acc[mt][nt] = __builtin_amdgcn_mfma_f32_16x16x32_bf16(
                    af[mt], bfr[nt], acc[mt][nt], 0, 0, 0);
    }

    if (mode == 0) {
        #pragma unroll
        for (int nt = 0; nt < 4; ++nt) {
            const int colx = col0 + wn * 64 + nt * 16 + cl;
            const float bb = b[colx];
            #pragma unroll
            for (int mt = 0; mt < 4; ++mt) {
                #pragma unroll
                for (int rr = 0; rr < 4; ++rr) {
                    int row = row0 + wm * 64 + mt * 16 + quad * 4 + rr;
                    if (row < N)
                        outb[(size_t)row * C + colx] =
                            (unsigned short)f2bf(fmaxf(acc[mt][nt][rr] + bb, 0.0f));
                }
            }
        }
    } else {
        float bv[4], wv2[4];
        #pragma unroll
        for (int nt = 0; nt < 4; ++nt) {
            const int colx = col0 + wn * 64 + nt * 16 + cl;
            bv[nt] = b[colx];
            wv2[nt] = Wo[colx];
        }
        #pragma unroll
        for (int mt = 0; mt < 4; ++mt) {
            #pragma unroll
            for (int rr = 0; rr < 4; ++rr) {
                float s = 0.0f;
                #pragma unroll
                for (int nt = 0; nt < 4; ++nt)
                    s += fmaxf(acc[mt][nt][rr] + bv[nt], 0.0f) * wv2[nt];
                s += __shfl_xor(s, 1);
                s += __shfl_xor(s, 2);
                s += __shfl_xor(s, 4);
                s += __shfl_xor(s, 8);
                int row = row0 + wm * 64 + mt * 16 + quad * 4 + rr;
                if (cl == 0 && row < N) atomicAdd(&logit[row], s);
            }
        }
    }
}

// ---------------- layer-2: 128x256 tile, A-in-LDS + B-in-regs --------------
// C = relu([A0|A1] @ W^T + b); logit[row] += sum_col C[row,col]*Wo[col].
// W = Wf fragment-packed (see cvt). 512 thr = 8 waves (2 wr x 4 wc),
// wave tile 64x64, BK=32, 32 K-tiles. LDS: A only, 3 x 8KB. 2+ blocks/CU.
// Phase t: [vmcnt(5)][barrier] RD_A(t%3) STG_A(t+2) MFMA(t; bq=B(t))
//          LDB(t+1 -> bq).
// Gate proof: VMEM queue at top of phase t (oldest first):
//   A(t), B(t-1)x4, A(t+1), B(t)x4  -> vmcnt(5) drains A(t)+B(t-1).
// bq->MFMA dep: compiler-counted vmcnt (one-phase lead >> L2 latency; W hot).
// A overwrite WAR: STG_A(t+2) hits buf((t-1)%3); phase t-1 reads retired
// before each wave's MFMA(t-1) (compiler lgkmcnt) hence before its phase-t
// barrier arrival; STG issues after that barrier.

#define STGA(kt) do {                                                          \
    const unsigned short* _p = ((kt) < 16) ? (A0 + ((kt) << 5))                \
                                           : (A1 + (((kt) - 16) << 5));        \
    GLOAD_LDS16(_p + offA, lds + ((kt) % 3) * 8192 + w * 1024);                \
} while (0)

#define LDB(kt) do {                                                           \
    _Pragma("unroll")                                                          \
    for (int _n = 0; _n < 4; ++_n)                                             \
        bq[_n] = *(const bf16x8*)(W +                                          \
            (((size_t)(kt) * 8 + gB) * 4 + _n) * 512 + l * 8);                 \
} while (0)

#define RDA(bf) do {                                                           \
    _Pragma("unroll")                                                          \
    for (int _m = 0; _m < 4; ++_m)                                             \
        af[_m] = *(const bf16x8*)(lds + (bf) * 8192 + aoff + _m * 1024);       \
} while (0)

#define MM16B() do {                                                           \
    _Pragma("unroll")                                                          \
    for (int _m = 0; _m < 4; ++_m)                                             \
        _Pragma("unroll")                                                      \
        for (int _n = 0; _n < 4; ++_n)                                         \
            acc[_m][_n] = __builtin_amdgcn_mfma_f32_16x16x32_bf16(             \
                af[_m], bq[_n], acc[_m][_n], 0, 0, 0);                         \
} while (0)

#define PHASE4(t, stage) do {                                                  \
    __builtin_amdgcn_sched_barrier(0);                                         \
    asm volatile("s_waitcnt vmcnt(5)" ::: "memory");                           \
    __builtin_amdgcn_s_barrier();                                              \
    __builtin_amdgcn_sched_barrier(0);                                         \
    RDA((t) % 3);                                                              \
    if (stage) STGA((t) + 2);                                                  \
    __builtin_amdgcn_s_setprio(1);                                             \
    MM16B();                                                                   \
    __builtin_amdgcn_s_setprio(0);                                             \
    if ((t) + 1 < 32) LDB((t) + 1);                                            \
} while (0)

__global__ __launch_bounds__(512, 4) void gemm2_breg(
    const unsigned short* __restrict__ A0,   // h1b [N,512] bf16
    const unsigned short* __restrict__ A1,   // n2b [N,512] bf16
    const unsigned short* __restrict__ W,    // Wf fragment-packed [512*1024]
    const float* __restrict__ b,             // b2 [512]
    const float* __restrict__ Wo,            // [512]
    float* __restrict__ logit,               // [N]
    int N)
{
    __shared__ char lds[24576];              // A: 3 x 8KB

    // bijective XCD swizzle (m204): contiguous virt chunk per XCD; the two
    // col-siblings of a row-tile are consecutive virt -> same XCD (A L2 reuse)
    const int nwg  = ((N + 127) >> 7) * 2;
    const int orig = blockIdx.x;
    const int xcd = orig & 7, lnum = orig >> 3;
    const int q = nwg >> 3, r = nwg & 7;
    const int virt = (xcd < r ? xcd * (q + 1) : r * (q + 1) + (xcd - r) * q) + lnum;
    const int row0 = (virt >> 1) << 7;       // 128-row tile
    const int col0 = (virt & 1) << 8;        // 256-col tile

    const int tid = threadIdx.x;
    const int w = tid >> 6, l = tid & 63;
    const int wr = w >> 2, wc = w & 3;       // 2x4 wave grid, 64x64 wave tile
    const int cl = l & 15, quad = l >> 4;
    const int gB = (col0 >> 6) + wc;         // 64-col group for B frags

    // ---- A staging (inverse-swizzled global source; linear LDS dest) ----
    // dest: row = w*16 + (l>>2), slot = l&3; (row>>1)&3 == (l>>3)&3 ->
    // logical col slot = (l&3) ^ ((l>>3)&3); c_log elements = 8 * that.
    const int c_log = (((l & 3) ^ ((l >> 3) & 3))) * 8;
    int ra = row0 + w * 16 + (l >> 2);
    if (ra > N - 1) ra = N - 1;              // clamp; epilogue guards row<N
    const size_t offA = (size_t)ra * 512 + c_log;

    // ---- A ds_read: phys = logical ^ (((row>>1)&3)<<4); (row>>1)&3=(cl>>1)&3
    const int swz  = ((cl >> 1) & 3) << 4;
    const int aoff = (((wr * 64 + cl) * 64) + quad * 16) ^ swz;   // + mt*1024

    f32x4 acc[4][4];
    #pragma unroll
    for (int mt = 0; mt < 4; ++mt)
        #pragma unroll
        for (int nt = 0; nt < 4; ++nt)
            acc[mt][nt] = (f32x4){0.f, 0.f, 0.f, 0.f};

    bf16x8 af[4], bq[4];

    // ---- prologue: stage A tiles 0,1; load B(0) ----
    STGA(0); STGA(1);
    LDB(0);

    #pragma unroll
    for (int t = 0; t < 30; ++t)
        PHASE4(t, 1);
    PHASE4(30, 0);
    PHASE4(31, 0);
    asm volatile("s_waitcnt vmcnt(0)" ::: "memory");   // drain tail

    // ---- epilogue: fused ReLU + Wo dot + atomic row add ----
    float bv[4], wv[4];
    #pragma unroll
    for (int nt = 0; nt < 4; ++nt) {
        const int colx = col0 + wc * 64 + nt * 16 + cl;
        bv[nt] = b[colx];
        wv[nt] = Wo[colx];
    }
    #pragma unroll
    for (int mt = 0; mt < 4; ++mt) {
        #pragma unroll
        for (int rr = 0; rr < 4; ++rr) {
            float s = 0.0f;
            #pragma unroll
            for (int nt = 0; nt < 4; ++nt)
                s += fmaxf(acc[mt][nt][rr] + bv[nt], 0.0f) * wv[nt];
            s += __shfl_xor(s, 1);
            s += __shfl_xor(s, 2);
            s += __shfl_xor(s, 4);
            s += __shfl_xor(s, 8);
            const int row = row0 + wr * 64 + mt * 16 + quad * 4 + rr;
            if (cl == 0 && row < N) atomicAdd(&logit[row], s);
        }
    }
}

__global__ void head_kernel(const float* __restrict__ logit, const float* __restrict__ bo,
                            float* __restrict__ out, int N) {
    int i = blockIdx.x * 256 + threadIdx.x;
    if (i < N) out[i] = 1.0f / (1.0f + expf(-(logit[i] + bo[0])));
}

extern "C" void kernel_launch(void* const* d_in, const int* in_sizes, int n_in,
                              void* d_out, int out_size, void* d_ws, size_t ws_size,
                              hipStream_t stream) {
    const float* x  = (const float*)d_in[0];
    const int*   ei = (const int*)d_in[1];
    const float* W1 = (const float*)d_in[2];
    const float* b1 = (const float*)d_in[3];
    const float* W2 = (const float*)d_in[4];
    const float* b2 = (const float*)d_in[5];
    const float* Wo = (const float*)d_in[6];
    const float* bo = (const float*)d_in[7];
    float* out = (float*)d_out;

    const int N = in_sizes[0] / 128;   // 50000
    const int E = in_sizes[1] / 2;     // 400000
    const int* src = ei;
    const int* dst = ei + E;

    char* ws = (char*)d_ws;
    size_t off = 0;
    auto alloc = [&](size_t bytes) {
        void* p = ws + off;
        off += (bytes + 255) & ~(size_t)255;
        return p;
    };
    int* deg      = (int*)alloc((size_t)N * 4);
    int* rowstart = (int*)alloc((size_t)(N + 1) * 4);
    int* cursor   = (int*)alloc((size_t)N * 4);
    int* partial  = (int*)alloc((size_t)64 * 4);
    int* ebuf     = (int*)alloc((size_t)E * 4);
    float* logit  = (float*)alloc((size_t)N * 4);
    unsigned short* xb  = (unsigned short*)alloc((size_t)N * 128 * 2);
    unsigned short* W1b = (unsigned short*)alloc((size_t)512 * 256 * 2);
    unsigned short* W2b = (unsigned short*)alloc((size_t)512 * 1024 * 2);   // Wf
    unsigned short* n1b = (unsigned short*)alloc((size_t)N * 128 * 2);
    unsigned short* h1b = (unsigned short*)alloc((size_t)N * 512 * 2);
    unsigned short* n2b = (unsigned short*)alloc((size_t)N * 512 * 2);
    (void)ws_size; (void)n_in; (void)out_size;

    hipMemsetAsync(deg,   0, (size_t)N * 4, stream);
    hipMemsetAsync(logit, 0, (size_t)N * 4, stream);

    // fused: cvt x/W1/W2(frag-pack) -> bf16  +  deg histogram
    const int na4 = N * 128 / 4, nb4 = 512 * 256 / 4, nc4 = 512 * 1024 / 4;
    const int cvt_blocks  = ceil_div(na4 + nb4 + nc4, 256);
    const int hist_blocks = ceil_div(E, 256);
    cvt3_hist_kernel<<<cvt_blocks + hist_blocks, 256, 0, stream>>>(
        x, xb, na4, W1, W1b, nb4, W2, W2b, nc4, dst, deg, E, cvt_blocks);

    // CSR build (hierarchical scan)
    const int P = ceil_div(N, 1024);   // 49
    chunk_reduce<<<P, 256, 0, stream>>>(deg, partial, N);
    partial_scan<<<1, 64, 0, stream>>>(partial, rowstart + N, P);
    chunk_scan<<<P, 256, 0, stream>>>(deg, partial, rowstart, cursor, N);
    bucket_kernel<<<ceil_div(E, 256), 256, 0, stream>>>(src, dst, cursor, ebuf, E);

    // layer 1: 128^2-tile kernel (K=256, small) — XCD-swizzled 1D grid
    const int nrow = ceil_div(N, 128);              // 391
    const int gblocks = ceil_div(nrow, 8) * 8 * 4;  // 1568
    gather_mean_128<<<ceil_div(N * 64, 256), 256, 0, stream>>>(rowstart, ebuf,
                                                               (const unsigned*)xb, (unsigned*)n1b, N);
    gemm_mfma<<<gblocks, 256, 0, stream>>>(xb, n1b, W1b, b1, h1b, nullptr, nullptr,
                                           N, 128, 128, 512, 0);

    // layer 2 + fused head: XCD-sliced gather, then A-in-LDS + B-in-regs GEMM
    const int gw = 8 * ceil_div(N, 4 * ROWS_PW);    // 8 slices x row-groups
    gather_mean_512s<<<gw, 256, 0, stream>>>(rowstart, ebuf,
                                             (const unsigned*)h1b, (unsigned*)n2b, N);
    const int g2 = ceil_div(N, 128) * 2;            // 782 blocks
    gemm2_breg<<<g2, 512, 0, stream>>>(h1b, n2b, W2b, b2, Wo, logit, N);

    head_kernel<<<ceil_div(N, 256), 256, 0, stream>>>(logit, bo, out, N);
}

// Round 7
// 317.083 us; speedup vs baseline: 1.3820x; 1.3820x over previous
//
#include <hip/hip_runtime.h>
#include <math.h>

// ---------------------------------------------------------------------------
// GraphSAGE fraud detector. CSR-gather aggregation + bf16 MFMA GEMMs.
// R23: revert R22's XCD-sliced gather (FETCH 188->110MB but dur 64.5->175us:
// 4B/lane loads = 4x instructions at 1/4 width + 8x ebuf re-walks ->
// issue-bound, occupancy 76%/HBM 12%). Keep 16B/lane full-row layout and
// attack the REAL limiter instead: mean degree = 8, so R21's >=8-edge unroll
// leaves ~half the rows in a serial 1-edge-dependent-chain tail ->
// latency-bound (47% HBM, 39% occ). Fix: masked batch-of-8 -- every row
// issues ceil(deg/8) batches of 8 INDEPENDENT uint4 loads (indices clamped
// to e1-1, contributions masked by sel FMA). Clamped dups are L1 hits.
// Same treatment for gather_mean_128.
// R21 (kept): layer-2 GEMM A-in-LDS(3x8KB)+B-in-regs from fragment-packed
// Wf (off = ((((t*8+g)*4+nt)*4+quad)*16+cl)*8+j); vmcnt(5) gate; 2 bl/CU.
// MFMA 16x16x32 bf16: A-frag A[m=lane&15][k=quad*8+j]; C/D col=lane&15,
// row=quad*4+reg (m89/m97-verified layouts).
// ---------------------------------------------------------------------------

typedef __attribute__((ext_vector_type(8))) short bf16x8;   // 8 bf16, 4 VGPRs
typedef __attribute__((ext_vector_type(4))) float f32x4;

static inline int ceil_div(int a, int b) { return (a + b - 1) / b; }

__device__ inline float bf2f_lo(unsigned u) { return __builtin_bit_cast(float, u << 16); }
__device__ inline float bf2f_hi(unsigned u) { return __builtin_bit_cast(float, u & 0xffff0000u); }
__device__ inline unsigned f2bf(float f) {   // RNE round to bf16, bits in low 16
    unsigned u = __builtin_bit_cast(unsigned, f);
    u += 0x7fffu + ((u >> 16) & 1u);
    return u >> 16;
}

// async global->LDS, 16 B per lane; LDS dest = wave-uniform base + lane*16
#define GLOAD_LDS16(gp, lp)                                                   \
    __builtin_amdgcn_global_load_lds(                                         \
        (__attribute__((address_space(1))) void*)(gp),                        \
        (__attribute__((address_space(3))) void*)(lp), 16, 0, 0)

// ---------------- fused cvt(x,W1,W2) + deg histogram ----------------
// W2 branch packs into the Wf fragment-linear layout (see header).

__global__ void cvt3_hist_kernel(const float* __restrict__ a, unsigned short* __restrict__ ao, int na4,
                                 const float* __restrict__ b, unsigned short* __restrict__ bo, int nb4,
                                 const float* __restrict__ c, unsigned short* __restrict__ co, int nc4,
                                 const int* __restrict__ dst, int* __restrict__ deg, int E,
                                 int cvt_blocks) {
    if ((int)blockIdx.x < cvt_blocks) {
        int i = blockIdx.x * 256 + threadIdx.x;
        if (i < na4 + nb4) {
            const float* in; unsigned short* out; int k;
            if (i < na4) { in = a; out = ao; k = i; }
            else         { in = b; out = bo; k = i - na4; }
            float4 v = ((const float4*)in)[k];
            ushort4 o;
            o.x = (unsigned short)f2bf(v.x);
            o.y = (unsigned short)f2bf(v.y);
            o.z = (unsigned short)f2bf(v.z);
            o.w = (unsigned short)f2bf(v.w);
            ((ushort4*)out)[k] = o;
        } else if (i < na4 + nb4 + nc4) {
            int kk = i - na4 - nb4;            // float4 idx into W2 [512][1024]
            float4 v = ((const float4*)c)[kk];
            ushort4 o;
            o.x = (unsigned short)f2bf(v.x);
            o.y = (unsigned short)f2bf(v.y);
            o.z = (unsigned short)f2bf(v.z);
            o.w = (unsigned short)f2bf(v.w);
            const int cc = kk >> 8;            // row (col of GEMM-B), 0..511
            const int kq = kk & 255;           // float4 within row
            const int t    = kq >> 3;          // k-tile of 32
            const int quad = (kq >> 1) & 3;
            const int j0   = (kq & 1) * 4;
            const int g  = cc >> 6, nt = (cc >> 4) & 3, cl = cc & 15;
            const size_t off =
                ((((size_t)(t * 8 + g) * 4 + nt) * 4 + quad) * 16 + cl) * 8 + j0;
            *(ushort4*)(co + off) = o;
        }
    } else {
        int e = (blockIdx.x - cvt_blocks) * 256 + threadIdx.x;
        if (e < E) atomicAdd(&deg[dst[e]], 1);
    }
}

// ---------------- CSR build ----------------

// per-1024-chunk sums
__global__ __launch_bounds__(256) void chunk_reduce(const int* __restrict__ deg,
                                                    int* __restrict__ partial, int N) {
    int base = blockIdx.x * 1024;
    int s = 0;
    for (int i = threadIdx.x; i < 1024; i += 256) {
        int idx = base + i;
        if (idx < N) s += deg[idx];
    }
    #pragma unroll
    for (int off = 32; off; off >>= 1) s += __shfl_down(s, off);
    __shared__ int ws[4];
    if ((threadIdx.x & 63) == 0) ws[threadIdx.x >> 6] = s;
    __syncthreads();
    if (threadIdx.x == 0) partial[blockIdx.x] = ws[0] + ws[1] + ws[2] + ws[3];
}

// exclusive scan of P<=64 partials (one wave); writes rowstart[N]=total
__global__ void partial_scan(int* __restrict__ partial, int* __restrict__ rowstartN, int P) {
    int lane = threadIdx.x;
    int v = (lane < P) ? partial[lane] : 0;
    int incl = v;
    #pragma unroll
    for (int off = 1; off < 64; off <<= 1) {
        int t = __shfl_up(incl, off);
        if (lane >= off) incl += t;
    }
    if (lane < P) partial[lane] = incl - v;
    if (lane == 63) *rowstartN = incl;
}

// per-chunk exclusive scan + global offset; writes rowstart and cursor
__global__ __launch_bounds__(256) void chunk_scan(const int* __restrict__ deg,
                                                  const int* __restrict__ partial,
                                                  int* __restrict__ rowstart,
                                                  int* __restrict__ cursor, int N) {
    int base = blockIdx.x * 1024 + threadIdx.x * 4;
    int v[4];
    #pragma unroll
    for (int j = 0; j < 4; ++j) {
        int i = base + j;
        v[j] = (i < N) ? deg[i] : 0;
    }
    int mysum = v[0] + v[1] + v[2] + v[3];
    int incl = mysum;
    int lane = threadIdx.x & 63, wave = threadIdx.x >> 6;
    #pragma unroll
    for (int off = 1; off < 64; off <<= 1) {
        int t = __shfl_up(incl, off);
        if (lane >= off) incl += t;
    }
    __shared__ int ws[4];
    if (lane == 63) ws[wave] = incl;
    __syncthreads();
    int run = partial[blockIdx.x] + incl - mysum;
    for (int w = 0; w < wave; ++w) run += ws[w];
    #pragma unroll
    for (int j = 0; j < 4; ++j) {
        int i = base + j;
        if (i < N) { rowstart[i] = run; cursor[i] = run; }
        run += v[j];
    }
}

__global__ void bucket_kernel(const int* __restrict__ src, const int* __restrict__ dst,
                              int* __restrict__ cursor, int* __restrict__ ebuf, int E) {
    int e = blockIdx.x * 256 + threadIdx.x;
    if (e < E) {
        int pos = atomicAdd(&cursor[dst[e]], 1);
        ebuf[pos] = src[e];
    }
}

// ---------------- gather means (masked batch-of-8, R23) ----------------

// one wave per dst row; bf16 xb [N,128] -> bf16 mean [N,128]; fp32 accum.
// Every row issues ceil(deg/8) batches of 8 independent loads (clamped idx,
// sel-masked accumulate) -> no serial tail, ~1 latency round-trip per row.
__global__ void gather_mean_128(const int* __restrict__ rowstart, const int* __restrict__ ebuf,
                                const unsigned* __restrict__ featb, unsigned* __restrict__ outb, int N) {
    int w = (blockIdx.x * blockDim.x + threadIdx.x) >> 6;
    int lane = threadIdx.x & 63;
    if (w >= N) return;
    int e0 = rowstart[w], e1 = rowstart[w + 1];
    float ax = 0.0f, ay = 0.0f;
    for (int i = e0; i < e1; i += 8) {
        int idx[8];
        #pragma unroll
        for (int u = 0; u < 8; ++u) {
            int t = i + u;
            idx[u] = ebuf[t < e1 ? t : e1 - 1];
        }
        unsigned v[8];
        #pragma unroll
        for (int u = 0; u < 8; ++u)
            v[u] = featb[(size_t)idx[u] * 64 + lane];
        #pragma unroll
        for (int u = 0; u < 8; ++u) {
            const float s = (i + u < e1) ? 1.0f : 0.0f;
            ax += s * bf2f_lo(v[u]);
            ay += s * bf2f_hi(v[u]);
        }
    }
    float inv = 1.0f / fmaxf((float)(e1 - e0), 1.0f);
    outb[(size_t)w * 64 + lane] = f2bf(ax * inv) | (f2bf(ay * inv) << 16);
}

// one wave per dst row; bf16 feat [N,512] -> bf16 mean [N,512]; fp32 accum.
// Masked batch-of-8 (see gather_mean_128).
__global__ void gather_mean_512(const int* __restrict__ rowstart, const int* __restrict__ ebuf,
                                const unsigned short* __restrict__ featb,
                                unsigned short* __restrict__ outb, int N) {
    int w = (blockIdx.x * blockDim.x + threadIdx.x) >> 6;
    int lane = threadIdx.x & 63;
    if (w >= N) return;
    int e0 = rowstart[w], e1 = rowstart[w + 1];
    float a[8] = {0, 0, 0, 0, 0, 0, 0, 0};
    const uint4* base = (const uint4*)featb;     // 512 bf16/row = 64 uint4/row
    for (int i = e0; i < e1; i += 8) {
        int idx[8];
        #pragma unroll
        for (int u = 0; u < 8; ++u) {
            int t = i + u;
            idx[u] = ebuf[t < e1 ? t : e1 - 1];
        }
        uint4 v[8];
        #pragma unroll
        for (int u = 0; u < 8; ++u)
            v[u] = base[(size_t)idx[u] * 64 + lane];
        #pragma unroll
        for (int u = 0; u < 8; ++u) {
            const float s = (i + u < e1) ? 1.0f : 0.0f;
            a[0] += s * bf2f_lo(v[u].x); a[1] += s * bf2f_hi(v[u].x);
            a[2] += s * bf2f_lo(v[u].y); a[3] += s * bf2f_hi(v[u].y);
            a[4] += s * bf2f_lo(v[u].z); a[5] += s * bf2f_hi(v[u].z);
            a[6] += s * bf2f_lo(v[u].w); a[7] += s * bf2f_hi(v[u].w);
        }
    }
    float inv = 1.0f / fmaxf((float)(e1 - e0), 1.0f);
    uint4 o;
    o.x = f2bf(a[0] * inv) | (f2bf(a[1] * inv) << 16);
    o.y = f2bf(a[2] * inv) | (f2bf(a[3] * inv) << 16);
    o.z = f2bf(a[4] * inv) | (f2bf(a[5] * inv) << 16);
    o.w = f2bf(a[6] * inv) | (f2bf(a[7] * inv) << 16);
    ((uint4*)outb)[(size_t)w * 64 + lane] = o;
}

// ---------------- bf16 MFMA GEMM (R12-exact: BK=32, XCD swizzle) -----------
// Retained for layer 1 (K=256).
__global__ __launch_bounds__(256) void gemm_mfma(
    const unsigned short* __restrict__ A0,   // [N, K0] bf16
    const unsigned short* __restrict__ A1,   // [N, K1] bf16, K1 == K0
    const unsigned short* __restrict__ W,    // [C, K0+K1] bf16 row-major
    const float* __restrict__ b,             // [C] fp32
    unsigned short* __restrict__ outb,       // [N, C] bf16 (mode 0)
    const float* __restrict__ Wo,            // [C] fp32    (mode 1)
    float* __restrict__ logit,               // [N] fp32    (mode 1)
    int N, int K0, int K1, int C, int mode)
{
    // --- XCD-aware decode ---
    const int nrow = (N + 127) >> 7;
    const int id   = blockIdx.x;
    const int rowb = ((id >> 5) << 3) + (id & 7);   // rslot*8 + xcd
    const int colb = (id >> 3) & 3;
    if (rowb >= nrow) return;

    const int K = K0 + K1;
    const int S = K0;               // row stride of both A0 and A1
    __shared__ short As[2][4096];   // [128][32] per buffer, 8 KB
    __shared__ short Bs[2][4096];

    const int tid  = threadIdx.x;
    const int lane = tid & 63;
    const int wave = tid >> 6;
    const int wm = wave & 1, wn = wave >> 1;
    const int cl = lane & 15, quad = lane >> 4;
    const int row0 = rowb * 128;
    const int col0 = colb * 128;

    // staging: lane = 4r+j; wave w, load i covers tile rows w*32+i*16 .. +16
    const int r = lane >> 2;        // 0..15
    const int j = lane & 3;         // 16B chunk within the row's 64B K-slice
    const int trow0 = wave * 32 + r;
    const int trow1 = trow0 + 16;
    // clamp OOB tile rows to N-1 (loaded garbage discarded by epilogue guard)
    const int ar0 = (row0 + trow0 < N) ? row0 + trow0 : N - 1;
    const int ar1 = (row0 + trow1 < N) ? row0 + trow1 : N - 1;
    const size_t aoff0 = (size_t)ar0 * S + j * 8;
    const size_t aoff1 = (size_t)ar1 * S + j * 8;
    const size_t boff0 = (size_t)(col0 + trow0) * K + j * 8;
    const size_t boff1 = (size_t)(col0 + trow1) * K + j * 8;
    const int lds0 = (wave * 32) * 32;        // shorts; wave-uniform
    const int lds1 = (wave * 32 + 16) * 32;

    f32x4 acc[4][4];
    #pragma unroll
    for (int mt = 0; mt < 4; ++mt)
        #pragma unroll
        for (int nt = 0; nt < 4; ++nt)
            acc[mt][nt] = (f32x4){0.f, 0.f, 0.f, 0.f};

    // prologue: DMA tile 0 into buffer 0
    GLOAD_LDS16(A0 + aoff0, &As[0][lds0]);
    GLOAD_LDS16(A0 + aoff1, &As[0][lds1]);
    GLOAD_LDS16(W  + boff0, &Bs[0][lds0]);
    GLOAD_LDS16(W  + boff1, &Bs[0][lds1]);

    const int iters = K >> 5;
    for (int i = 0; i < iters; ++i) {
        const int cur = i & 1;
        // barrier drains tile i's DMA (vmcnt0) and fences tile i-1 frag reads
        __syncthreads();
        if (i + 1 < iters) {
            const int kn = (i + 1) << 5;
            const unsigned short* Ab = (kn < K0) ? (A0 + kn) : (A1 + (kn - K0));
            const unsigned short* Wb = W + kn;
            const int nb = cur ^ 1;
            GLOAD_LDS16(Ab + aoff0, &As[nb][lds0]);
            GLOAD_LDS16(Ab + aoff1, &As[nb][lds1]);
            GLOAD_LDS16(Wb + boff0, &Bs[nb][lds0]);
            GLOAD_LDS16(Wb + boff1, &Bs[nb][lds1]);
        }

        bf16x8 af[4], bfr[4];
        #pragma unroll
        for (int mt = 0; mt < 4; ++mt)
            af[mt] = *(const bf16x8*)&As[cur][(wm * 64 + mt * 16 + cl) * 32 + quad * 8];
        #pragma unroll
        for (int nt = 0; nt < 4; ++nt)
            bfr[nt] = *(const bf16x8*)&Bs[cur][(wn * 64 + nt * 16 + cl) * 32 + quad * 8];

        #pragma unroll
        for (int mt = 0; mt < 4; ++mt)
            #pragma unroll
            for (int nt = 0; nt < 4; ++nt)
                acc[mt][nt] = __builtin_amdgcn_mfma_f32_16x16x32_bf16(
                    af[mt], bfr[nt], acc[mt][nt], 0, 0, 0);
    }

    if (mode == 0) {
        #pragma unroll
        for (int nt = 0; nt < 4; ++nt) {
            const int colx = col0 + wn * 64 + nt * 16 + cl;
            const float bb = b[colx];
            #pragma unroll
            for (int mt = 0; mt < 4; ++mt) {
                #pragma unroll
                for (int rr = 0; rr < 4; ++rr) {
                    int row = row0 + wm * 64 + mt * 16 + quad * 4 + rr;
                    if (row < N)
                        outb[(size_t)row * C + colx] =
                            (unsigned short)f2bf(fmaxf(acc[mt][nt][rr] + bb, 0.0f));
                }
            }
        }
    } else {
        float bv[4], wv2[4];
        #pragma unroll
        for (int nt = 0; nt < 4; ++nt) {
            const int colx = col0 + wn * 64 + nt * 16 + cl;
            bv[nt] = b[colx];
            wv2[nt] = Wo[colx];
        }
        #pragma unroll
        for (int mt = 0; mt < 4; ++mt) {
            #pragma unroll
            for (int rr = 0; rr < 4; ++rr) {
                float s = 0.0f;
                #pragma unroll
                for (int nt = 0; nt < 4; ++nt)
                    s += fmaxf(acc[mt][nt][rr] + bv[nt], 0.0f) * wv2[nt];
                s += __shfl_xor(s, 1);
                s += __shfl_xor(s, 2);
                s += __shfl_xor(s, 4);
                s += __shfl_xor(s, 8);
                int row = row0 + wm * 64 + mt * 16 + quad * 4 + rr;
                if (cl == 0 && row < N) atomicAdd(&logit[row], s);
            }
        }
    }
}

// ---------------- layer-2: 128x256 tile, A-in-LDS + B-in-regs --------------
// C = relu([A0|A1] @ W^T + b); logit[row] += sum_col C[row,col]*Wo[col].
// W = Wf fragment-packed (see cvt). 512 thr = 8 waves (2 wr x 4 wc),
// wave tile 64x64, BK=32, 32 K-tiles. LDS: A only, 3 x 8KB. 2+ blocks/CU.
// Phase t: [vmcnt(5)][barrier] RD_A(t%3) STG_A(t+2) MFMA(t; bq=B(t))
//          LDB(t+1 -> bq).
// Gate proof: VMEM queue at top of phase t (oldest first):
//   A(t), B(t-1)x4, A(t+1), B(t)x4  -> vmcnt(5) drains A(t)+B(t-1).
// bq->MFMA dep: compiler-counted vmcnt (one-phase lead >> L2 latency; W hot).
// A overwrite WAR: STG_A(t+2) hits buf((t-1)%3); phase t-1 reads retired
// before each wave's MFMA(t-1) (compiler lgkmcnt) hence before its phase-t
// barrier arrival; STG issues after that barrier.

#define STGA(kt) do {                                                          \
    const unsigned short* _p = ((kt) < 16) ? (A0 + ((kt) << 5))                \
                                           : (A1 + (((kt) - 16) << 5));        \
    GLOAD_LDS16(_p + offA, lds + ((kt) % 3) * 8192 + w * 1024);                \
} while (0)

#define LDB(kt) do {                                                           \
    _Pragma("unroll")                                                          \
    for (int _n = 0; _n < 4; ++_n)                                             \
        bq[_n] = *(const bf16x8*)(W +                                          \
            (((size_t)(kt) * 8 + gB) * 4 + _n) * 512 + l * 8);                 \
} while (0)

#define RDA(bf) do {                                                           \
    _Pragma("unroll")                                                          \
    for (int _m = 0; _m < 4; ++_m)                                             \
        af[_m] = *(const bf16x8*)(lds + (bf) * 8192 + aoff + _m * 1024);       \
} while (0)

#define MM16B() do {                                                           \
    _Pragma("unroll")                                                          \
    for (int _m = 0; _m < 4; ++_m)                                             \
        _Pragma("unroll")                                                      \
        for (int _n = 0; _n < 4; ++_n)                                         \
            acc[_m][_n] = __builtin_amdgcn_mfma_f32_16x16x32_bf16(             \
                af[_m], bq[_n], acc[_m][_n], 0, 0, 0);                         \
} while (0)

#define PHASE4(t, stage) do {                                                  \
    __builtin_amdgcn_sched_barrier(0);                                         \
    asm volatile("s_waitcnt vmcnt(5)" ::: "memory");                           \
    __builtin_amdgcn_s_barrier();                                              \
    __builtin_amdgcn_sched_barrier(0);                                         \
    RDA((t) % 3);                                                              \
    if (stage) STGA((t) + 2);                                                  \
    __builtin_amdgcn_s_setprio(1);                                             \
    MM16B();                                                                   \
    __builtin_amdgcn_s_setprio(0);                                             \
    if ((t) + 1 < 32) LDB((t) + 1);                                            \
} while (0)

__global__ __launch_bounds__(512, 4) void gemm2_breg(
    const unsigned short* __restrict__ A0,   // h1b [N,512] bf16
    const unsigned short* __restrict__ A1,   // n2b [N,512] bf16
    const unsigned short* __restrict__ W,    // Wf fragment-packed [512*1024]
    const float* __restrict__ b,             // b2 [512]
    const float* __restrict__ Wo,            // [512]
    float* __restrict__ logit,               // [N]
    int N)
{
    __shared__ char lds[24576];              // A: 3 x 8KB

    // bijective XCD swizzle (m204): contiguous virt chunk per XCD; the two
    // col-siblings of a row-tile are consecutive virt -> same XCD (A L2 reuse)
    const int nwg  = ((N + 127) >> 7) * 2;
    const int orig = blockIdx.x;
    const int xcd = orig & 7, lnum = orig >> 3;
    const int q = nwg >> 3, r = nwg & 7;
    const int virt = (xcd < r ? xcd * (q + 1) : r * (q + 1) + (xcd - r) * q) + lnum;
    const int row0 = (virt >> 1) << 7;       // 128-row tile
    const int col0 = (virt & 1) << 8;        // 256-col tile

    const int tid = threadIdx.x;
    const int w = tid >> 6, l = tid & 63;
    const int wr = w >> 2, wc = w & 3;       // 2x4 wave grid, 64x64 wave tile
    const int cl = l & 15, quad = l >> 4;
    const int gB = (col0 >> 6) + wc;         // 64-col group for B frags

    // ---- A staging (inverse-swizzled global source; linear LDS dest) ----
    // dest: row = w*16 + (l>>2), slot = l&3; (row>>1)&3 == (l>>3)&3 ->
    // logical col slot = (l&3) ^ ((l>>3)&3); c_log elements = 8 * that.
    const int c_log = (((l & 3) ^ ((l >> 3) & 3))) * 8;
    int ra = row0 + w * 16 + (l >> 2);
    if (ra > N - 1) ra = N - 1;              // clamp; epilogue guards row<N
    const size_t offA = (size_t)ra * 512 + c_log;

    // ---- A ds_read: phys = logical ^ (((row>>1)&3)<<4); (row>>1)&3=(cl>>1)&3
    const int swz  = ((cl >> 1) & 3) << 4;
    const int aoff = (((wr * 64 + cl) * 64) + quad * 16) ^ swz;   // + mt*1024

    f32x4 acc[4][4];
    #pragma unroll
    for (int mt = 0; mt < 4; ++mt)
        #pragma unroll
        for (int nt = 0; nt < 4; ++nt)
            acc[mt][nt] = (f32x4){0.f, 0.f, 0.f, 0.f};

    bf16x8 af[4], bq[4];

    // ---- prologue: stage A tiles 0,1; load B(0) ----
    STGA(0); STGA(1);
    LDB(0);

    #pragma unroll
    for (int t = 0; t < 30; ++t)
        PHASE4(t, 1);
    PHASE4(30, 0);
    PHASE4(31, 0);
    asm volatile("s_waitcnt vmcnt(0)" ::: "memory");   // drain tail

    // ---- epilogue: fused ReLU + Wo dot + atomic row add ----
    float bv[4], wv[4];
    #pragma unroll
    for (int nt = 0; nt < 4; ++nt) {
        const int colx = col0 + wc * 64 + nt * 16 + cl;
        bv[nt] = b[colx];
        wv[nt] = Wo[colx];
    }
    #pragma unroll
    for (int mt = 0; mt < 4; ++mt) {
        #pragma unroll
        for (int rr = 0; rr < 4; ++rr) {
            float s = 0.0f;
            #pragma unroll
            for (int nt = 0; nt < 4; ++nt)
                s += fmaxf(acc[mt][nt][rr] + bv[nt], 0.0f) * wv[nt];
            s += __shfl_xor(s, 1);
            s += __shfl_xor(s, 2);
            s += __shfl_xor(s, 4);
            s += __shfl_xor(s, 8);
            const int row = row0 + wr * 64 + mt * 16 + quad * 4 + rr;
            if (cl == 0 && row < N) atomicAdd(&logit[row], s);
        }
    }
}

__global__ void head_kernel(const float* __restrict__ logit, const float* __restrict__ bo,
                            float* __restrict__ out, int N) {
    int i = blockIdx.x * 256 + threadIdx.x;
    if (i < N) out[i] = 1.0f / (1.0f + expf(-(logit[i] + bo[0])));
}

extern "C" void kernel_launch(void* const* d_in, const int* in_sizes, int n_in,
                              void* d_out, int out_size, void* d_ws, size_t ws_size,
                              hipStream_t stream) {
    const float* x  = (const float*)d_in[0];
    const int*   ei = (const int*)d_in[1];
    const float* W1 = (const float*)d_in[2];
    const float* b1 = (const float*)d_in[3];
    const float* W2 = (const float*)d_in[4];
    const float* b2 = (const float*)d_in[5];
    const float* Wo = (const float*)d_in[6];
    const float* bo = (const float*)d_in[7];
    float* out = (float*)d_out;

    const int N = in_sizes[0] / 128;   // 50000
    const int E = in_sizes[1] / 2;     // 400000
    const int* src = ei;
    const int* dst = ei + E;

    char* ws = (char*)d_ws;
    size_t off = 0;
    auto alloc = [&](size_t bytes) {
        void* p = ws + off;
        off += (bytes + 255) & ~(size_t)255;
        return p;
    };
    int* deg      = (int*)alloc((size_t)N * 4);
    int* rowstart = (int*)alloc((size_t)(N + 1) * 4);
    int* cursor   = (int*)alloc((size_t)N * 4);
    int* partial  = (int*)alloc((size_t)64 * 4);
    int* ebuf     = (int*)alloc((size_t)E * 4);
    float* logit  = (float*)alloc((size_t)N * 4);
    unsigned short* xb  = (unsigned short*)alloc((size_t)N * 128 * 2);
    unsigned short* W1b = (unsigned short*)alloc((size_t)512 * 256 * 2);
    unsigned short* W2b = (unsigned short*)alloc((size_t)512 * 1024 * 2);   // Wf
    unsigned short* n1b = (unsigned short*)alloc((size_t)N * 128 * 2);
    unsigned short* h1b = (unsigned short*)alloc((size_t)N * 512 * 2);
    unsigned short* n2b = (unsigned short*)alloc((size_t)N * 512 * 2);
    (void)ws_size; (void)n_in; (void)out_size;

    hipMemsetAsync(deg,   0, (size_t)N * 4, stream);
    hipMemsetAsync(logit, 0, (size_t)N * 4, stream);

    // fused: cvt x/W1/W2(frag-pack) -> bf16  +  deg histogram
    const int na4 = N * 128 / 4, nb4 = 512 * 256 / 4, nc4 = 512 * 1024 / 4;
    const int cvt_blocks  = ceil_div(na4 + nb4 + nc4, 256);
    const int hist_blocks = ceil_div(E, 256);
    cvt3_hist_kernel<<<cvt_blocks + hist_blocks, 256, 0, stream>>>(
        x, xb, na4, W1, W1b, nb4, W2, W2b, nc4, dst, deg, E, cvt_blocks);

    // CSR build (hierarchical scan)
    const int P = ceil_div(N, 1024);   // 49
    chunk_reduce<<<P, 256, 0, stream>>>(deg, partial, N);
    partial_scan<<<1, 64, 0, stream>>>(partial, rowstart + N, P);
    chunk_scan<<<P, 256, 0, stream>>>(deg, partial, rowstart, cursor, N);
    bucket_kernel<<<ceil_div(E, 256), 256, 0, stream>>>(src, dst, cursor, ebuf, E);

    // layer 1: 128^2-tile kernel (K=256, small) — XCD-swizzled 1D grid
    const int nrow = ceil_div(N, 128);              // 391
    const int gblocks = ceil_div(nrow, 8) * 8 * 4;  // 1568
    gather_mean_128<<<ceil_div(N * 64, 256), 256, 0, stream>>>(rowstart, ebuf,
                                                               (const unsigned*)xb, (unsigned*)n1b, N);
    gemm_mfma<<<gblocks, 256, 0, stream>>>(xb, n1b, W1b, b1, h1b, nullptr, nullptr,
                                           N, 128, 128, 512, 0);

    // layer 2 + fused head: gather (masked batch-of-8), then B-in-regs GEMM
    gather_mean_512<<<ceil_div(N * 64, 256), 256, 0, stream>>>(rowstart, ebuf, h1b, n2b, N);
    const int g2 = ceil_div(N, 128) * 2;            // 782 blocks
    gemm2_breg<<<g2, 512, 0, stream>>>(h1b, n2b, W2b, b2, Wo, logit, N);

    head_kernel<<<ceil_div(N, 256), 256, 0, stream>>>(logit, bo, out, N);
}